// Round 2
// baseline (396.069 us; speedup 1.0000x reference)
//
#include <hip/hip_runtime.h>

// VQ nearest-codebook via bf16-split MFMA + margin-based exact rescue.
// x: (2, 40, 64, 1500) f32 ; cb: (40, 1024, 64) f32
// out[b,band,c,t] = cb[band, argmin_k ||x[b,band,:,t]-cb[band,k]||^2, c]
//
// score(k) = ||c_k||^2 - 2*dot  (|| x ||^2 is argmin-invariant)
// approx dot = xh*ch + xh*cl + xl*ch  (3 chained bf16 MFMAs, fp32 acc)
// |approx - exact| <= ~5e-4 ; MARGIN = 4e-3 covers it with 8x safety.

#define NBAND  40
#define CH     64
#define TT     1500
#define NCODE  1024
#define MT     128     // t-tile per block
#define KC     128     // codes per LDS chunk
#define PAD    72      // LDS row stride in bf16 elems (144B, 16B-aligned)
#define MARGIN 4e-3f

typedef short v8s __attribute__((ext_vector_type(8)));
typedef float v4f __attribute__((ext_vector_type(4)));

__device__ __forceinline__ unsigned short f2bf(float f) {
    unsigned u = __float_as_uint(f);
    return (unsigned short)((u + 0x7FFFu + ((u >> 16) & 1u)) >> 16);   // RNE
}
__device__ __forceinline__ float bf2f(unsigned short h) {
    return __uint_as_float(((unsigned)h) << 16);
}
__device__ __forceinline__ unsigned ford(float f) {   // monotone float->uint
    unsigned u = __float_as_uint(f);
    return (u & 0x80000000u) ? ~u : (u | 0x80000000u);
}
__device__ __forceinline__ float finv(unsigned u) {
    return (u & 0x80000000u) ? __uint_as_float(u & 0x7FFFFFFFu) : __uint_as_float(~u);
}
__device__ __forceinline__ unsigned long long packsk(float f, unsigned k) {
    return ((unsigned long long)ford(f) << 32) | (unsigned long long)k;
}

__global__ __launch_bounds__(256, 2)
void vq_mfma_kernel(const float* __restrict__ x,
                    const float* __restrict__ cb,
                    float* __restrict__ out) {
    __shared__ unsigned long long best_s[MT];          // packed (ordered score, idx)
    __shared__ unsigned short XH_s[MT * PAD];
    __shared__ unsigned short XL_s[MT * PAD];
    __shared__ unsigned short CBH_s[KC * PAD];
    __shared__ unsigned short CBL_s[KC * PAD];
    __shared__ float    c2half_s[256];                 // per half-row |c|^2 partials
    __shared__ unsigned mu_s[MT];                      // ordered-uint approx min per t
    __shared__ unsigned cnt_s[MT];                     // candidates within margin
    __shared__ float    xrow_s[CH];                    // pass-3 x row

    const int tile  = blockIdx.x;
    const int band  = blockIdx.y;
    const int batch = blockIdx.z;
    const int t0    = tile * MT;

    const int tid  = threadIdx.x;
    const int wave = tid >> 6;
    const int lane = tid & 63;
    const int quad = lane >> 4;
    const int col  = lane & 15;

    if (tid < MT) mu_s[tid] = 0xFFFFFFFFu;

    // ---- stage x tile as bf16 hi/lo, layout [t][c] (padded rows) ----
    {
        const int c  = tid & 63;
        const int g  = tid >> 6;
        const float* src = x + ((size_t)(batch * NBAND + band) * CH + c) * TT + t0;
        #pragma unroll
        for (int i = 0; i < 8; ++i) {
            const int tq = g + 4 * i;           // 0..31
            const int t  = tq * 4;
            float4 v = make_float4(0.f, 0.f, 0.f, 0.f);
            if (t0 + t + 3 < TT) v = *(const float4*)(src + t);   // TT%4==0: no partial quads
            const float vv[4] = {v.x, v.y, v.z, v.w};
            #pragma unroll
            for (int j = 0; j < 4; ++j) {
                const unsigned short h = f2bf(vv[j]);
                const unsigned short l = f2bf(vv[j] - bf2f(h));
                XH_s[(t + j) * PAD + c] = h;
                XL_s[(t + j) * PAD + c] = l;
            }
        }
    }
    __syncthreads();

    // ---- A fragments (x) live in registers for the whole kernel ----
    // A[m][k]: m = lane&15 (+16*mi), k = quad*8+j (+32*ks)
    v8s ah[2][2], al[2][2];
    #pragma unroll
    for (int mi = 0; mi < 2; ++mi)
        #pragma unroll
        for (int ks = 0; ks < 2; ++ks) {
            const int off = (wave * 32 + mi * 16 + col) * PAD + ks * 32 + quad * 8;
            ah[mi][ks] = *(const v8s*)&XH_s[off];
            al[mi][ks] = *(const v8s*)&XL_s[off];
        }

    float vmin[8], mlim[8];
    #pragma unroll
    for (int i = 0; i < 8; ++i) vmin[i] = 3.4028235e38f;

    auto phase_loop = [&](const int PHASE) {
        for (int kc = 0; kc < NCODE; kc += KC) {
            __syncthreads();   // previous chunk's readers done
            // ---- stage codebook chunk as bf16 hi/lo + |c|^2 half-sums ----
            {
                const int k    = tid >> 1;
                const int half = (tid & 1) * 32;
                const float* src = cb + ((size_t)(band * NCODE + kc + k)) * CH + half;
                float ssq = 0.f;
                #pragma unroll
                for (int i = 0; i < 8; ++i) {
                    const float4 v = *(const float4*)(src + i * 4);
                    const float vv[4] = {v.x, v.y, v.z, v.w};
                    ushort4 hh, ll;
                    unsigned short* hp = (unsigned short*)&hh;
                    unsigned short* lp = (unsigned short*)&ll;
                    #pragma unroll
                    for (int j = 0; j < 4; ++j) {
                        const unsigned short h = f2bf(vv[j]);
                        hp[j] = h;
                        lp[j] = f2bf(vv[j] - bf2f(h));
                        ssq = fmaf(vv[j], vv[j], ssq);
                    }
                    *(ushort4*)&CBH_s[k * PAD + half + i * 4] = hh;
                    *(ushort4*)&CBL_s[k * PAD + half + i * 4] = ll;
                }
                c2half_s[tid] = ssq;
            }
            __syncthreads();

            #pragma unroll
            for (int ng = 0; ng < 4; ++ng) {
                const int n0 = ng * 32;
                // B[k][n]: n = lane&15 (+16*ni), k = quad*8+j (+32*ks) -> CB rows
                v8s bh[2][2], bl[2][2];
                #pragma unroll
                for (int ni = 0; ni < 2; ++ni)
                    #pragma unroll
                    for (int ks = 0; ks < 2; ++ks) {
                        const int off = (n0 + ni * 16 + col) * PAD + ks * 32 + quad * 8;
                        bh[ni][ks] = *(const v8s*)&CBH_s[off];
                        bl[ni][ks] = *(const v8s*)&CBL_s[off];
                    }
                v4f acc[2][2];
                #pragma unroll
                for (int mi = 0; mi < 2; ++mi)
                    #pragma unroll
                    for (int ni = 0; ni < 2; ++ni) acc[mi][ni] = (v4f){0.f, 0.f, 0.f, 0.f};
                #pragma unroll
                for (int ks = 0; ks < 2; ++ks) {
                    #pragma unroll
                    for (int mi = 0; mi < 2; ++mi)
                        #pragma unroll
                        for (int ni = 0; ni < 2; ++ni)
                            acc[mi][ni] = __builtin_amdgcn_mfma_f32_16x16x32_bf16(
                                ah[mi][ks], bh[ni][ks], acc[mi][ni], 0, 0, 0);
                    #pragma unroll
                    for (int mi = 0; mi < 2; ++mi)
                        #pragma unroll
                        for (int ni = 0; ni < 2; ++ni)
                            acc[mi][ni] = __builtin_amdgcn_mfma_f32_16x16x32_bf16(
                                ah[mi][ks], bl[ni][ks], acc[mi][ni], 0, 0, 0);
                    #pragma unroll
                    for (int mi = 0; mi < 2; ++mi)
                        #pragma unroll
                        for (int ni = 0; ni < 2; ++ni)
                            acc[mi][ni] = __builtin_amdgcn_mfma_f32_16x16x32_bf16(
                                al[mi][ks], bh[ni][ks], acc[mi][ni], 0, 0, 0);
                }
                float c2v[2];
                #pragma unroll
                for (int ni = 0; ni < 2; ++ni) {
                    const int kidx = n0 + ni * 16 + col;
                    c2v[ni] = c2half_s[2 * kidx] + c2half_s[2 * kidx + 1];
                }
                // D[row][col]: t = wave*32 + mi*16 + quad*4 + r ; code = kc + n0 + ni*16 + col
                #pragma unroll
                for (int mi = 0; mi < 2; ++mi)
                    #pragma unroll
                    for (int ni = 0; ni < 2; ++ni)
                        #pragma unroll
                        for (int r = 0; r < 4; ++r) {
                            const float score = fmaf(-2.f, acc[mi][ni][r], c2v[ni]);
                            if (PHASE == 1) {
                                vmin[mi * 4 + r] = fminf(vmin[mi * 4 + r], score);
                            } else {
                                if (score <= mlim[mi * 4 + r]) {
                                    const int tl = wave * 32 + mi * 16 + quad * 4 + r;
                                    const unsigned kg = (unsigned)(kc + n0 + ni * 16 + col);
                                    atomicAdd(&cnt_s[tl], 1u);
                                    atomicMin(&best_s[tl], packsk(score, kg));
                                }
                            }
                        }
            }
        }
    };

    // ---- phase 1: approx min per t ----
    phase_loop(1);
    #pragma unroll
    for (int mi = 0; mi < 2; ++mi)
        #pragma unroll
        for (int r = 0; r < 4; ++r) {
            const int tl = wave * 32 + mi * 16 + quad * 4 + r;
            atomicMin(&mu_s[tl], ford(vmin[mi * 4 + r]));
        }
    if (tid < MT) { cnt_s[tid] = 0u; best_s[tid] = ~0ULL; }
    __syncthreads();
    #pragma unroll
    for (int mi = 0; mi < 2; ++mi)
        #pragma unroll
        for (int r = 0; r < 4; ++r) {
            const int tl = wave * 32 + mi * 16 + quad * 4 + r;
            mlim[mi * 4 + r] = finv(mu_s[tl]) + MARGIN;
        }

    // ---- phase 2: candidate capture (scores bitwise-identical to phase 1) ----
    phase_loop(2);
    __syncthreads();

    // ---- pass 3: exact fp32 rescore where >=2 candidates within margin (rare) ----
    for (int t = 0; t < MT; ++t) {
        if (cnt_s[t] >= 2u && t0 + t < TT) {
            if (tid < CH) xrow_s[tid] = x[((size_t)(batch * NBAND + band) * CH + tid) * TT + t0 + t];
            if (tid == CH) best_s[t] = ~0ULL;
            __syncthreads();
            #pragma unroll
            for (int i = 0; i < 4; ++i) {
                const int k = tid * 4 + i;
                const float* crow = cb + ((size_t)(band * NCODE + k)) * CH;
                float dot = 0.f, c2e = 0.f;
                #pragma unroll 8
                for (int c = 0; c < CH; ++c) {
                    const float cv = crow[c];
                    dot = fmaf(cv, xrow_s[c], dot);
                    c2e = fmaf(cv, cv, c2e);
                }
                atomicMin(&best_s[t], packsk(fmaf(-2.f, dot, c2e), (unsigned)k));
            }
            __syncthreads();
        }
    }
    __syncthreads();

    // ---- epilogue: gather winning codebook rows, transposed coalesced store ----
    {
        const int tloc  = tid & 127;
        const int chalf = tid >> 7;
        if (t0 + tloc < TT) {
            const unsigned idx = (unsigned)(best_s[tloc] & 0xFFFFFFFFull) & (NCODE - 1);
            const float* crow = cb + ((size_t)(band * NCODE + idx)) * CH;
            float* ob = out + ((size_t)(batch * NBAND + band) * CH) * TT + t0 + tloc;
            #pragma unroll
            for (int i = 0; i < 32; ++i) {
                const int c = chalf * 32 + i;
                ob[(size_t)c * TT] = crow[c];
            }
        }
    }
}

extern "C" void kernel_launch(void* const* d_in, const int* in_sizes, int n_in,
                              void* d_out, int out_size, void* d_ws, size_t ws_size,
                              hipStream_t stream) {
    const float* x  = (const float*)d_in[0];
    const float* cb = (const float*)d_in[1];
    float* out = (float*)d_out;
    dim3 grid((TT + MT - 1) / MT, NBAND, 2);
    vq_mfma_kernel<<<grid, dim3(256), 0, stream>>>(x, cb, out);
}

// Round 3
// 218.743 us; speedup vs baseline: 1.8107x; 1.8107x over previous
//
#include <hip/hip_runtime.h>

// VQ nearest-codebook, round 3: pre-swizzled bf16-split codebook in d_ws,
// barrier-free single-pass MFMA K-loop with register B-fragments,
// (min1,idx,min2) tracking + exact fp32 rescue for near-ties.
//
// x: (2, 40, 64, 1500) f32 ; cb: (40, 1024, 64) f32
// out[b,band,c,t] = cb[band, argmin_k ||x[b,band,:,t]-cb[band,k]||^2, c]

#define NBAND  40
#define CH     64
#define TT     1500
#define NCODE  1024
#define MT     128     // t-tile per block
#define PAD    68      // x-tile LDS row stride in ushorts (136 B -> bank rotate 2/row)
#define THRESH 1e-3f   // rescue margin; split err bound ~2e-4

typedef short v8s __attribute__((ext_vector_type(8)));
typedef float v4f __attribute__((ext_vector_type(4)));

// ws layout: CBF fragments [band][group 0..31][load 0..7][lane 0..63][8 ushorts]
//   load = ni*2+ks (hi) / 4+ni*2+ks (lo); content = plane[code=g*32+ni*16+(lane&15)][c=ks*32+(lane>>4)*8 ..+8]
// then C2 float[40*1024]
#define CBF_USHORTS ((size_t)NBAND * 32 * 8 * 64 * 8)       // 5,242,880
#define CBF_BYTES   (CBF_USHORTS * 2)                        // 10,485,760
#define WS_NEEDED   (CBF_BYTES + (size_t)NBAND * NCODE * 4)  // +163,840

__device__ __forceinline__ unsigned short f2bf(float f) {
    unsigned u = __float_as_uint(f);
    return (unsigned short)((u + 0x7FFFu + ((u >> 16) & 1u)) >> 16);   // RNE
}
__device__ __forceinline__ float bf2f(unsigned short h) {
    return __uint_as_float(((unsigned)h) << 16);
}
__device__ __forceinline__ unsigned ford(float f) {
    unsigned u = __float_as_uint(f);
    return (u & 0x80000000u) ? ~u : (u | 0x80000000u);
}
__device__ __forceinline__ unsigned long long packsk(float f, unsigned k) {
    return ((unsigned long long)ford(f) << 32) | (unsigned long long)k;
}

// ---------------- prep: split + swizzle codebook into ws ----------------
__global__ void vq_prep(const float* __restrict__ cb,
                        unsigned short* __restrict__ CBF,
                        float* __restrict__ C2) {
    const int g    = blockIdx.x;    // 0..31
    const int band = blockIdx.y;    // 0..39
    const int lane = threadIdx.x;   // 0..63
    const int col  = lane & 15;
    const int quad = lane >> 4;

    #pragma unroll
    for (int l = 0; l < 4; ++l) {
        const int ni = l >> 1, ks = l & 1;
        const int code = g * 32 + ni * 16 + col;
        const int c0   = ks * 32 + quad * 8;
        const float* src = cb + ((size_t)(band * NCODE + code)) * CH + c0;
        const float4 v0 = *(const float4*)src;
        const float4 v1 = *(const float4*)(src + 4);
        const float vv[8] = {v0.x, v0.y, v0.z, v0.w, v1.x, v1.y, v1.z, v1.w};
        union { unsigned short u[8]; v8s v; } hh, ll;
        #pragma unroll
        for (int j = 0; j < 8; ++j) {
            const unsigned short h = f2bf(vv[j]);
            hh.u[j] = h;
            ll.u[j] = f2bf(vv[j] - bf2f(h));
        }
        const size_t gb = (size_t)(band * 32 + g) * 8;
        *(v8s*)&CBF[(gb + l)     * 512 + lane * 8] = hh.v;
        *(v8s*)&CBF[(gb + 4 + l) * 512 + lane * 8] = ll.v;
    }
    if (lane < 32) {
        const int code = g * 32 + lane;
        const float* src = cb + ((size_t)(band * NCODE + code)) * CH;
        float s = 0.f;
        #pragma unroll 8
        for (int c = 0; c < CH; ++c) s = fmaf(src[c], src[c], s);
        C2[band * NCODE + code] = s;
    }
}

// ---------------- main ----------------
__global__ __launch_bounds__(256, 4)
void vq_main(const float* __restrict__ x,
             const float* __restrict__ cb,
             const unsigned short* __restrict__ CBF,
             const float* __restrict__ C2f,
             float* __restrict__ out) {
    __shared__ alignas(16) unsigned char SMEM[2 * MT * PAD * 2];   // 34816 B: x-tile, later reduce scratch
    __shared__ float c2_s[NCODE];                                  // 4 KB
    __shared__ unsigned long long best_s[MT];                      // packed (ordered score, idx)
    __shared__ unsigned amb_s[4];
    __shared__ float xrow_s[CH];

    unsigned short* XH_s = (unsigned short*)SMEM;
    unsigned short* XL_s = XH_s + MT * PAD;

    const int tile  = blockIdx.x;
    const int band  = blockIdx.y;
    const int batch = blockIdx.z;
    const int t0    = tile * MT;

    const int tid  = threadIdx.x;
    const int wave = tid >> 6;
    const int lane = tid & 63;
    const int quad = lane >> 4;
    const int col  = lane & 15;

    if (tid < 4) amb_s[tid] = 0u;
    // stage c2 (coalesced)
    {
        const float* src = C2f + band * NCODE;
        #pragma unroll
        for (int i = 0; i < 4; ++i) c2_s[tid + 256 * i] = src[tid + 256 * i];
    }
    // stage x tile as bf16 hi/lo, [t][c] padded rows
    {
        const int c = tid & 63;
        const int g = tid >> 6;
        const float* src = x + ((size_t)(batch * NBAND + band) * CH + c) * TT + t0;
        #pragma unroll
        for (int i = 0; i < 8; ++i) {
            const int t = (g + 4 * i) * 4;
            float4 v = make_float4(0.f, 0.f, 0.f, 0.f);
            if (t0 + t + 3 < TT) v = *(const float4*)(src + t);   // TT%4==0
            const float vv[4] = {v.x, v.y, v.z, v.w};
            #pragma unroll
            for (int j = 0; j < 4; ++j) {
                const unsigned short h = f2bf(vv[j]);
                XH_s[(t + j) * PAD + c] = h;
                XL_s[(t + j) * PAD + c] = f2bf(vv[j] - bf2f(h));
            }
        }
    }
    __syncthreads();

    // A fragments register-resident: A[m=lane&15][k=quad*8+j], m->t row, +16*mi, k +32*ks
    v8s ah[2][2], al[2][2];
    #pragma unroll
    for (int mi = 0; mi < 2; ++mi)
        #pragma unroll
        for (int ks = 0; ks < 2; ++ks) {
            const int off = (wave * 32 + mi * 16 + col) * PAD + ks * 32 + quad * 8;
            ah[mi][ks] = *(const v8s*)&XH_s[off];
            al[mi][ks] = *(const v8s*)&XL_s[off];
        }
    __syncthreads();   // x-tile fully consumed; SMEM free for reuse after loop

    float m1[8], m2[8];
    int   id8[8];
    #pragma unroll
    for (int i = 0; i < 8; ++i) { m1[i] = 3.4028235e38f; m2[i] = 3.4028235e38f; id8[i] = 0x7fffffff; }

    const unsigned short* fb = CBF + (size_t)(band * 32) * 8 * 512 + (size_t)lane * 8;

    // barrier-free K-loop: 32 groups of 32 codes
    for (int g = 0; g < 32; ++g) {
        const unsigned short* p = fb + (size_t)g * 8 * 512;
        v8s bh[2][2], bl[2][2];
        #pragma unroll
        for (int ni = 0; ni < 2; ++ni)
            #pragma unroll
            for (int ks = 0; ks < 2; ++ks) {
                bh[ni][ks] = *(const v8s*)(p + (ni * 2 + ks) * 512);
                bl[ni][ks] = *(const v8s*)(p + (4 + ni * 2 + ks) * 512);
            }
        v4f acc[2][2];
        #pragma unroll
        for (int mi = 0; mi < 2; ++mi)
            #pragma unroll
            for (int ni = 0; ni < 2; ++ni) acc[mi][ni] = (v4f){0.f, 0.f, 0.f, 0.f};
        #pragma unroll
        for (int ks = 0; ks < 2; ++ks) {
            #pragma unroll
            for (int mi = 0; mi < 2; ++mi)
                #pragma unroll
                for (int ni = 0; ni < 2; ++ni)
                    acc[mi][ni] = __builtin_amdgcn_mfma_f32_16x16x32_bf16(ah[mi][ks], bh[ni][ks], acc[mi][ni], 0, 0, 0);
            #pragma unroll
            for (int mi = 0; mi < 2; ++mi)
                #pragma unroll
                for (int ni = 0; ni < 2; ++ni)
                    acc[mi][ni] = __builtin_amdgcn_mfma_f32_16x16x32_bf16(ah[mi][ks], bl[ni][ks], acc[mi][ni], 0, 0, 0);
            #pragma unroll
            for (int mi = 0; mi < 2; ++mi)
                #pragma unroll
                for (int ni = 0; ni < 2; ++ni)
                    acc[mi][ni] = __builtin_amdgcn_mfma_f32_16x16x32_bf16(al[mi][ks], bh[ni][ks], acc[mi][ni], 0, 0, 0);
        }
        // scores + (m1, idx, m2) update; ni outer keeps k ascending per slot (first-min ties)
        #pragma unroll
        for (int ni = 0; ni < 2; ++ni) {
            const float c2v = c2_s[g * 32 + ni * 16 + col];
            const int   kg  = g * 32 + ni * 16 + col;
            #pragma unroll
            for (int mi = 0; mi < 2; ++mi)
                #pragma unroll
                for (int r = 0; r < 4; ++r) {
                    const int j = mi * 4 + r;
                    const float s = fmaf(-2.f, acc[mi][ni][r], c2v);
                    m2[j] = fminf(m2[j], fmaxf(s, m1[j]));
                    const bool lt = s < m1[j];
                    m1[j]  = lt ? s : m1[j];
                    id8[j] = lt ? kg : id8[j];
                }
        }
    }
    __syncthreads();   // all waves past x/c2 reads of SMEM region

    // cross-col reduction via LDS (alias SMEM): 16 partials per t
    float* RM1 = (float*)SMEM;            // [MT][16]
    float* RM2 = RM1 + MT * 16;           // [MT][16]
    int*   RI  = (int*)(RM2 + MT * 16);   // [MT][16]
    #pragma unroll
    for (int j = 0; j < 8; ++j) {
        const int t = wave * 32 + (j >> 2) * 16 + quad * 4 + (j & 3);
        RM1[t * 16 + col] = m1[j];
        RM2[t * 16 + col] = m2[j];
        RI [t * 16 + col] = id8[j];
    }
    __syncthreads();

    if (tid < MT) {
        const int t = tid;
        float M1 = RM1[t * 16], M2 = RM2[t * 16];
        int   I  = RI[t * 16];
        #pragma unroll
        for (int j = 1; j < 16; ++j) {
            const float a1 = RM1[t * 16 + j];
            const float a2 = RM2[t * 16 + j];
            const int   ai = RI [t * 16 + j];
            if (a1 < M1 || (a1 == M1 && ai < I)) { M2 = fminf(M2, M1); M1 = a1; I = ai; }
            else                                  { M2 = fminf(M2, a1); }
            M2 = fminf(M2, a2);
        }
        best_s[t] = packsk(M1, (unsigned)I);
        if ((M2 - M1) <= THRESH && t0 + t < TT)
            atomicOr(&amb_s[t >> 5], 1u << (t & 31));
    }
    __syncthreads();

    // exact fp32 rescue for near-ties (rare)
    for (int t = 0; t < MT; ++t) {
        if ((amb_s[t >> 5] >> (t & 31)) & 1u) {
            if (tid < CH) xrow_s[tid] = x[((size_t)(batch * NBAND + band) * CH + tid) * TT + t0 + t];
            if (tid == CH) best_s[t] = ~0ULL;
            __syncthreads();
            #pragma unroll
            for (int i = 0; i < 4; ++i) {
                const int k = tid * 4 + i;
                const float* crow = cb + ((size_t)(band * NCODE + k)) * CH;
                float dot = 0.f, c2e = 0.f;
                #pragma unroll 8
                for (int c = 0; c < CH; ++c) {
                    const float cv = crow[c];
                    dot = fmaf(cv, xrow_s[c], dot);
                    c2e = fmaf(cv, cv, c2e);
                }
                atomicMin(&best_s[t], packsk(fmaf(-2.f, dot, c2e), (unsigned)k));
            }
            __syncthreads();
        }
    }
    __syncthreads();

    // epilogue: gather winning rows, transposed coalesced store
    {
        const int tloc  = tid & 127;
        const int chalf = tid >> 7;
        if (t0 + tloc < TT) {
            const unsigned idx = (unsigned)(best_s[tloc] & 0xFFFFFFFFull) & (NCODE - 1);
            const float* crow = cb + ((size_t)(band * NCODE + idx)) * CH;
            float* ob = out + ((size_t)(batch * NBAND + band) * CH) * TT + t0 + tloc;
            #pragma unroll
            for (int i = 0; i < 32; ++i) {
                const int c = chalf * 32 + i;
                ob[(size_t)c * TT] = crow[c];
            }
        }
    }
}

// ---------------- fallback: round-1 fp32 kernel (proven correct, ~290 us) ----------------
#define TN 128
#define KC 128
__global__ __launch_bounds__(256, 2)
void vq_fp32_kernel(const float* __restrict__ x,
                    const float* __restrict__ cb,
                    float* __restrict__ out) {
    __shared__ float XT_s[CH * TN];
    __shared__ float CBT_s[CH * KC];
    __shared__ float c2part[256];
    const int tile = blockIdx.x, band = blockIdx.y, batch = blockIdx.z;
    const int t0 = tile * TN;
    const int tid = threadIdx.x;
    const int tx = tid & 15, ty = tid >> 4;
    {
        const int c = tid >> 2, q = tid & 3;
        const float* src = x + ((size_t)(batch * NBAND + band) * CH + c) * TT + t0;
        #pragma unroll
        for (int i = 0; i < 8; ++i) {
            const int t = q * 32 + i * 4;
            float4 v = make_float4(0.f, 0.f, 0.f, 0.f);
            if (t0 + t < TT) v = *(const float4*)(src + t);
            *(float4*)&XT_s[c * TN + t] = v;
        }
    }
    float vmin[8]; int vidx[8];
    #pragma unroll
    for (int i = 0; i < 8; ++i) { vmin[i] = 3.4e38f; vidx[i] = 0x7fffffff; }
    for (int kc = 0; kc < NCODE; kc += KC) {
        __syncthreads();
        {
            const int k = tid >> 1, ch0 = (tid & 1) * 32;
            const float* src = cb + ((size_t)(band * NCODE + kc + k)) * CH + ch0;
            float s = 0.f;
            #pragma unroll
            for (int i = 0; i < 8; ++i) {
                const float4 v = *(const float4*)(src + i * 4);
                const int c0 = ch0 + i * 4;
                CBT_s[(c0 + 0) * KC + k] = v.x; CBT_s[(c0 + 1) * KC + k] = v.y;
                CBT_s[(c0 + 2) * KC + k] = v.z; CBT_s[(c0 + 3) * KC + k] = v.w;
                s = fmaf(v.x, v.x, s); s = fmaf(v.y, v.y, s);
                s = fmaf(v.z, v.z, s); s = fmaf(v.w, v.w, s);
            }
            c2part[tid] = s;
        }
        __syncthreads();
        float acc[8][8];
        #pragma unroll
        for (int ii = 0; ii < 8; ++ii)
            #pragma unroll
            for (int jj = 0; jj < 8; ++jj) acc[ii][jj] = 0.f;
        #pragma unroll 4
        for (int c = 0; c < CH; ++c) {
            const float4 xa0 = *(const float4*)&XT_s[c * TN + tx * 4];
            const float4 xa1 = *(const float4*)&XT_s[c * TN + 64 + tx * 4];
            const float4 cv0 = *(const float4*)&CBT_s[c * KC + ty * 4];
            const float4 cv1 = *(const float4*)&CBT_s[c * KC + 64 + ty * 4];
            const float xa[8] = {xa0.x, xa0.y, xa0.z, xa0.w, xa1.x, xa1.y, xa1.z, xa1.w};
            const float cv[8] = {cv0.x, cv0.y, cv0.z, cv0.w, cv1.x, cv1.y, cv1.z, cv1.w};
            #pragma unroll
            for (int ii = 0; ii < 8; ++ii)
                #pragma unroll
                for (int jj = 0; jj < 8; ++jj) acc[ii][jj] = fmaf(xa[ii], cv[jj], acc[ii][jj]);
        }
        #pragma unroll
        for (int jj = 0; jj < 8; ++jj) {
            const int kl = (jj < 4) ? (ty * 4 + jj) : (64 + ty * 4 + (jj - 4));
            const float c2v = c2part[2 * kl] + c2part[2 * kl + 1];
            const int kglob = kc + kl;
            #pragma unroll
            for (int ii = 0; ii < 8; ++ii) {
                const float score = fmaf(-2.f, acc[ii][jj], c2v);
                if (score < vmin[ii]) { vmin[ii] = score; vidx[ii] = kglob; }
            }
        }
    }
    __syncthreads();
    float* redv = XT_s;
    int* redi = (int*)(XT_s + TN * 16);
    int* idxs = (int*)(XT_s + TN * 32);
    #pragma unroll
    for (int ii = 0; ii < 8; ++ii) {
        const int t = (ii < 4) ? (tx * 4 + ii) : (64 + tx * 4 + (ii - 4));
        redv[t * 16 + ty] = vmin[ii];
        redi[t * 16 + ty] = vidx[ii];
    }
    __syncthreads();
    if (tid < TN) {
        float bv = redv[tid * 16]; int bi = redi[tid * 16];
        #pragma unroll
        for (int j = 1; j < 16; ++j) {
            const float v = redv[tid * 16 + j]; const int id = redi[tid * 16 + j];
            if (v < bv || (v == bv && id < bi)) { bv = v; bi = id; }
        }
        idxs[tid] = bi;
    }
    __syncthreads();
    {
        const int tloc = tid & 127, chalf = tid >> 7;
        if (t0 + tloc < TT) {
            const int idx = idxs[tloc];
            const float* crow = cb + ((size_t)(band * NCODE + idx)) * CH;
            float* ob = out + ((size_t)(batch * NBAND + band) * CH) * TT + t0 + tloc;
            #pragma unroll
            for (int i = 0; i < 32; ++i) {
                const int c = chalf * 32 + i;
                ob[(size_t)c * TT] = crow[c];
            }
        }
    }
}

extern "C" void kernel_launch(void* const* d_in, const int* in_sizes, int n_in,
                              void* d_out, int out_size, void* d_ws, size_t ws_size,
                              hipStream_t stream) {
    const float* x  = (const float*)d_in[0];
    const float* cb = (const float*)d_in[1];
    float* out = (float*)d_out;
    dim3 grid((TT + MT - 1) / MT, NBAND, 2);
    if (ws_size >= WS_NEEDED) {
        unsigned short* CBF = (unsigned short*)d_ws;
        float* C2 = (float*)((char*)d_ws + CBF_BYTES);
        vq_prep<<<dim3(32, NBAND), dim3(64), 0, stream>>>(cb, CBF, C2);
        vq_main<<<grid, dim3(256), 0, stream>>>(x, cb, CBF, C2, out);
    } else {
        vq_fp32_kernel<<<grid, dim3(256), 0, stream>>>(x, cb, out);
    }
}

// Round 4
// 215.342 us; speedup vs baseline: 1.8393x; 1.0158x over previous
//
#include <hip/hip_runtime.h>

// VQ nearest-codebook, round 4: async global_load_lds double-buffered B-fragments
// (shared across waves, 1 barrier/group, prefetch issued AFTER the barrier so it
// overlaps compute), register A-fragments, (min1,idx,min2) + exact fp32 rescue.
//
// x: (2, 40, 64, 1500) f32 ; cb: (40, 1024, 64) f32
// out[b,band,c,t] = cb[band, argmin_k ||x[b,band,:,t]-cb[band,k]||^2, c]

#define NBAND  40
#define CH     64
#define TT     1500
#define NCODE  1024
#define MT     128     // t-tile per block
#define PAD    68      // x staging row stride (ushorts)
#define THRESH 1e-3f   // rescue margin; bf16-split err bound ~2e-4

typedef short v8s __attribute__((ext_vector_type(8)));
typedef float v4f __attribute__((ext_vector_type(4)));

// ws: CBF fragments [band][group 0..31][plane 0..7][lane 0..63][8 ushorts]
//   plane = ni*2+ks (hi) / 4+ni*2+ks (lo); content = code g*32+ni*16+(lane&15),
//   c = ks*32+(lane>>4)*8 .. +8.  Then C2 float[40*1024].
#define CBF_USHORTS ((size_t)NBAND * 32 * 8 * 64 * 8)
#define CBF_BYTES   (CBF_USHORTS * 2)
#define WS_NEEDED   (CBF_BYTES + (size_t)NBAND * NCODE * 4)

__device__ __forceinline__ unsigned short f2bf(float f) {
    unsigned u = __float_as_uint(f);
    return (unsigned short)((u + 0x7FFFu + ((u >> 16) & 1u)) >> 16);   // RNE
}
__device__ __forceinline__ float bf2f(unsigned short h) {
    return __uint_as_float(((unsigned)h) << 16);
}
__device__ __forceinline__ unsigned ford(float f) {
    unsigned u = __float_as_uint(f);
    return (u & 0x80000000u) ? ~u : (u | 0x80000000u);
}
__device__ __forceinline__ unsigned long long packsk(float f, unsigned k) {
    return ((unsigned long long)ford(f) << 32) | (unsigned long long)k;
}

typedef __attribute__((address_space(1))) const unsigned char* gas_p;
typedef __attribute__((address_space(3))) unsigned char*       las_p;
__device__ __forceinline__ void async_ld16(const void* g, void* l) {
    __builtin_amdgcn_global_load_lds((gas_p)g, (las_p)l, 16, 0, 0);
}

// ---------------- prep: split + swizzle codebook into ws, shuffle-reduced C2 ----------------
__global__ __launch_bounds__(256)
void vq_prep(const float* __restrict__ cb,
             unsigned short* __restrict__ CBF,
             float* __restrict__ C2) {
    const int band = blockIdx.y;
    const int g    = blockIdx.x * 4 + (threadIdx.x >> 6);   // grid.x = 8
    const int lane = threadIdx.x & 63;
    const int col  = lane & 15;
    const int quad = lane >> 4;

    float sq[2] = {0.f, 0.f};
    #pragma unroll
    for (int l = 0; l < 4; ++l) {
        const int ni = l >> 1, ks = l & 1;
        const int code = g * 32 + ni * 16 + col;
        const int c0   = ks * 32 + quad * 8;
        const float* src = cb + ((size_t)(band * NCODE + code)) * CH + c0;
        const float4 v0 = *(const float4*)src;
        const float4 v1 = *(const float4*)(src + 4);
        const float vv[8] = {v0.x, v0.y, v0.z, v0.w, v1.x, v1.y, v1.z, v1.w};
        union { unsigned short u[8]; v8s v; } hh, ll;
        #pragma unroll
        for (int j = 0; j < 8; ++j) {
            const unsigned short h = f2bf(vv[j]);
            hh.u[j] = h;
            ll.u[j] = f2bf(vv[j] - bf2f(h));
            sq[ni] = fmaf(vv[j], vv[j], sq[ni]);
        }
        const size_t gb = (size_t)(band * 32 + g) * 8;
        *(v8s*)&CBF[(gb + l)     * 512 + lane * 8] = hh.v;
        *(v8s*)&CBF[(gb + 4 + l) * 512 + lane * 8] = ll.v;
    }
    // reduce |c|^2 over the 4 quads (lane = quad*16+col)
    #pragma unroll
    for (int ni = 0; ni < 2; ++ni) {
        sq[ni] += __shfl_xor(sq[ni], 16);
        sq[ni] += __shfl_xor(sq[ni], 32);
    }
    if (quad == 0) {
        C2[band * NCODE + g * 32 + col]      = sq[0];
        C2[band * NCODE + g * 32 + 16 + col] = sq[1];
    }
}

// ---------------- main ----------------
__global__ __launch_bounds__(256, 4)
void vq_main(const float* __restrict__ x,
             const float* __restrict__ cb,
             const unsigned short* __restrict__ CBF,
             const float* __restrict__ C2f,
             float* __restrict__ out) {
    __shared__ alignas(16) unsigned char SMEM[MT * PAD * 2 * 2];   // 34816 B
    __shared__ float c2_s[NCODE];
    __shared__ unsigned long long best_s[MT];
    __shared__ unsigned amb_s[4];
    __shared__ float xrow_s[CH];

    unsigned short* XH_s = (unsigned short*)SMEM;
    unsigned short* XL_s = XH_s + MT * PAD;

    const int tile  = blockIdx.x;
    const int band  = blockIdx.y;
    const int batch = blockIdx.z;
    const int t0    = tile * MT;

    const int tid  = threadIdx.x;
    const int wave = tid >> 6;
    const int lane = tid & 63;
    const int quad = lane >> 4;
    const int col  = lane & 15;

    if (tid < 4) amb_s[tid] = 0u;
    {
        const float* src = C2f + band * NCODE;
        #pragma unroll
        for (int i = 0; i < 4; ++i) c2_s[tid + 256 * i] = src[tid + 256 * i];
    }
    // stage x tile as bf16 hi/lo, [t][c] padded rows
    {
        const int c = tid & 63;
        const int g = tid >> 6;
        const float* src = x + ((size_t)(batch * NBAND + band) * CH + c) * TT + t0;
        #pragma unroll
        for (int i = 0; i < 8; ++i) {
            const int t = (g + 4 * i) * 4;
            float4 v = make_float4(0.f, 0.f, 0.f, 0.f);
            if (t0 + t + 3 < TT) v = *(const float4*)(src + t);   // TT%4==0
            const float vv[4] = {v.x, v.y, v.z, v.w};
            #pragma unroll
            for (int j = 0; j < 4; ++j) {
                const unsigned short h = f2bf(vv[j]);
                XH_s[(t + j) * PAD + c] = h;
                XL_s[(t + j) * PAD + c] = f2bf(vv[j] - bf2f(h));
            }
        }
    }
    __syncthreads();

    // A fragments register-resident
    v8s ah[2][2], al[2][2];
    #pragma unroll
    for (int mi = 0; mi < 2; ++mi)
        #pragma unroll
        for (int ks = 0; ks < 2; ++ks) {
            const int off = (wave * 32 + mi * 16 + col) * PAD + ks * 32 + quad * 8;
            ah[mi][ks] = *(const v8s*)&XH_s[off];
            al[mi][ks] = *(const v8s*)&XL_s[off];
        }
    __syncthreads();   // x-tile consumed; SMEM now the fragment double-buffer

    float m1[8], m2[8];
    int   id8[8];
    #pragma unroll
    for (int i = 0; i < 8; ++i) { m1[i] = 3.4028235e38f; m2[i] = 3.4028235e38f; id8[i] = 0x7fffffff; }

    // fragment source: this band, per-lane 16B
    const unsigned short* fbase = CBF + (size_t)(band * 32) * 4096 + (size_t)lane * 8;
    unsigned short* LBUF = (unsigned short*)SMEM;   // 2 x 8192 B

    // wave w stages planes {2w, 2w+1} of a group: 2 x global_load_lds_dwordx4
    auto stage_group = [&](int g, int buf) {
        #pragma unroll
        for (int i = 0; i < 2; ++i) {
            const int p = wave * 2 + i;
            async_ld16(fbase + (size_t)g * 4096 + p * 512,
                       LBUF + (size_t)buf * 4096 + p * 512);   // HW adds lane*16
        }
    };

    stage_group(0, 0);

    for (int g = 0; g < 32; ++g) {
        __syncthreads();                         // own async loads drained; buf[g&1] complete for all
        if (g + 1 < 32) stage_group(g + 1, (g + 1) & 1);   // flies during compute(g)

        const unsigned short* lb = LBUF + (size_t)(g & 1) * 4096 + lane * 8;
        v4f acc[2][2];
        #pragma unroll
        for (int mi = 0; mi < 2; ++mi)
            #pragma unroll
            for (int ni = 0; ni < 2; ++ni) acc[mi][ni] = (v4f){0.f, 0.f, 0.f, 0.f};

        #pragma unroll
        for (int ks = 0; ks < 2; ++ks) {
            const v8s bh0 = *(const v8s*)(lb + (0 * 2 + ks) * 512);
            const v8s bh1 = *(const v8s*)(lb + (1 * 2 + ks) * 512);
            const v8s bl0 = *(const v8s*)(lb + (4 + 0 * 2 + ks) * 512);
            const v8s bl1 = *(const v8s*)(lb + (4 + 1 * 2 + ks) * 512);
            #pragma unroll
            for (int mi = 0; mi < 2; ++mi) {
                acc[mi][0] = __builtin_amdgcn_mfma_f32_16x16x32_bf16(ah[mi][ks], bh0, acc[mi][0], 0, 0, 0);
                acc[mi][1] = __builtin_amdgcn_mfma_f32_16x16x32_bf16(ah[mi][ks], bh1, acc[mi][1], 0, 0, 0);
            }
            #pragma unroll
            for (int mi = 0; mi < 2; ++mi) {
                acc[mi][0] = __builtin_amdgcn_mfma_f32_16x16x32_bf16(ah[mi][ks], bl0, acc[mi][0], 0, 0, 0);
                acc[mi][1] = __builtin_amdgcn_mfma_f32_16x16x32_bf16(ah[mi][ks], bl1, acc[mi][1], 0, 0, 0);
            }
            #pragma unroll
            for (int mi = 0; mi < 2; ++mi) {
                acc[mi][0] = __builtin_amdgcn_mfma_f32_16x16x32_bf16(al[mi][ks], bh0, acc[mi][0], 0, 0, 0);
                acc[mi][1] = __builtin_amdgcn_mfma_f32_16x16x32_bf16(al[mi][ks], bh1, acc[mi][1], 0, 0, 0);
            }
        }
        // (m1, idx, m2) update; k ascending per slot -> strict '<' keeps first-min
        #pragma unroll
        for (int ni = 0; ni < 2; ++ni) {
            const float c2v = c2_s[g * 32 + ni * 16 + col];
            const int   kg  = g * 32 + ni * 16 + col;
            #pragma unroll
            for (int mi = 0; mi < 2; ++mi)
                #pragma unroll
                for (int r = 0; r < 4; ++r) {
                    const int j = mi * 4 + r;
                    const float s = fmaf(-2.f, acc[mi][ni][r], c2v);
                    m2[j] = fminf(m2[j], fmaxf(s, m1[j]));
                    const bool lt = s < m1[j];
                    m1[j]  = lt ? s : m1[j];
                    id8[j] = lt ? kg : id8[j];
                }
        }
    }
    __syncthreads();

    // cross-col reduction (alias SMEM)
    float* RM1 = (float*)SMEM;            // [MT][16]
    float* RM2 = RM1 + MT * 16;
    int*   RI  = (int*)(RM2 + MT * 16);
    #pragma unroll
    for (int j = 0; j < 8; ++j) {
        const int t = wave * 32 + (j >> 2) * 16 + quad * 4 + (j & 3);
        RM1[t * 16 + col] = m1[j];
        RM2[t * 16 + col] = m2[j];
        RI [t * 16 + col] = id8[j];
    }
    __syncthreads();

    if (tid < MT) {
        const int t = tid;
        float M1 = RM1[t * 16], M2 = RM2[t * 16];
        int   I  = RI[t * 16];
        #pragma unroll
        for (int j = 1; j < 16; ++j) {
            const float a1 = RM1[t * 16 + j];
            const float a2 = RM2[t * 16 + j];
            const int   ai = RI [t * 16 + j];
            if (a1 < M1 || (a1 == M1 && ai < I)) { M2 = fminf(M2, M1); M1 = a1; I = ai; }
            else                                  { M2 = fminf(M2, a1); }
            M2 = fminf(M2, a2);
        }
        best_s[t] = packsk(M1, (unsigned)I);
        if ((M2 - M1) <= THRESH && t0 + t < TT)
            atomicOr(&amb_s[t >> 5], 1u << (t & 31));
    }
    __syncthreads();

    // exact fp32 rescue for near-ties (rare)
    for (int t = 0; t < MT; ++t) {
        if ((amb_s[t >> 5] >> (t & 31)) & 1u) {
            if (tid < CH) xrow_s[tid] = x[((size_t)(batch * NBAND + band) * CH + tid) * TT + t0 + t];
            if (tid == CH) best_s[t] = ~0ULL;
            __syncthreads();
            #pragma unroll
            for (int i = 0; i < 4; ++i) {
                const int k = tid * 4 + i;
                const float* crow = cb + ((size_t)(band * NCODE + k)) * CH;
                float dot = 0.f, c2e = 0.f;
                #pragma unroll 8
                for (int c = 0; c < CH; ++c) {
                    const float cv = crow[c];
                    dot = fmaf(cv, xrow_s[c], dot);
                    c2e = fmaf(cv, cv, c2e);
                }
                atomicMin(&best_s[t], packsk(fmaf(-2.f, dot, c2e), (unsigned)k));
            }
            __syncthreads();
        }
    }
    __syncthreads();

    // epilogue: gather winning rows, transposed coalesced store
    {
        const int tloc  = tid & 127;
        const int chalf = tid >> 7;
        if (t0 + tloc < TT) {
            const unsigned idx = (unsigned)(best_s[tloc] & 0xFFFFFFFFull) & (NCODE - 1);
            const float* crow = cb + ((size_t)(band * NCODE + idx)) * CH;
            float* ob = out + ((size_t)(batch * NBAND + band) * CH) * TT + t0 + tloc;
            #pragma unroll
            for (int i = 0; i < 32; ++i) {
                const int c = chalf * 32 + i;
                ob[(size_t)c * TT] = crow[c];
            }
        }
    }
}

// ---------------- fallback: round-1 fp32 kernel (proven, ~290 us) ----------------
#define TN 128
#define KC 128
__global__ __launch_bounds__(256, 2)
void vq_fp32_kernel(const float* __restrict__ x,
                    const float* __restrict__ cb,
                    float* __restrict__ out) {
    __shared__ float XT_s[CH * TN];
    __shared__ float CBT_s[CH * KC];
    __shared__ float c2part[256];
    const int tile = blockIdx.x, band = blockIdx.y, batch = blockIdx.z;
    const int t0 = tile * TN;
    const int tid = threadIdx.x;
    const int tx = tid & 15, ty = tid >> 4;
    {
        const int c = tid >> 2, q = tid & 3;
        const float* src = x + ((size_t)(batch * NBAND + band) * CH + c) * TT + t0;
        #pragma unroll
        for (int i = 0; i < 8; ++i) {
            const int t = q * 32 + i * 4;
            float4 v = make_float4(0.f, 0.f, 0.f, 0.f);
            if (t0 + t < TT) v = *(const float4*)(src + t);
            *(float4*)&XT_s[c * TN + t] = v;
        }
    }
    float vmin[8]; int vidx[8];
    #pragma unroll
    for (int i = 0; i < 8; ++i) { vmin[i] = 3.4e38f; vidx[i] = 0x7fffffff; }
    for (int kc = 0; kc < NCODE; kc += KC) {
        __syncthreads();
        {
            const int k = tid >> 1, ch0 = (tid & 1) * 32;
            const float* src = cb + ((size_t)(band * NCODE + kc + k)) * CH + ch0;
            float s = 0.f;
            #pragma unroll
            for (int i = 0; i < 8; ++i) {
                const float4 v = *(const float4*)(src + i * 4);
                const int c0 = ch0 + i * 4;
                CBT_s[(c0 + 0) * KC + k] = v.x; CBT_s[(c0 + 1) * KC + k] = v.y;
                CBT_s[(c0 + 2) * KC + k] = v.z; CBT_s[(c0 + 3) * KC + k] = v.w;
                s = fmaf(v.x, v.x, s); s = fmaf(v.y, v.y, s);
                s = fmaf(v.z, v.z, s); s = fmaf(v.w, v.w, s);
            }
            c2part[tid] = s;
        }
        __syncthreads();
        float acc[8][8];
        #pragma unroll
        for (int ii = 0; ii < 8; ++ii)
            #pragma unroll
            for (int jj = 0; jj < 8; ++jj) acc[ii][jj] = 0.f;
        #pragma unroll 4
        for (int c = 0; c < CH; ++c) {
            const float4 xa0 = *(const float4*)&XT_s[c * TN + tx * 4];
            const float4 xa1 = *(const float4*)&XT_s[c * TN + 64 + tx * 4];
            const float4 cv0 = *(const float4*)&CBT_s[c * KC + ty * 4];
            const float4 cv1 = *(const float4*)&CBT_s[c * KC + 64 + ty * 4];
            const float xa[8] = {xa0.x, xa0.y, xa0.z, xa0.w, xa1.x, xa1.y, xa1.z, xa1.w};
            const float cv[8] = {cv0.x, cv0.y, cv0.z, cv0.w, cv1.x, cv1.y, cv1.z, cv1.w};
            #pragma unroll
            for (int ii = 0; ii < 8; ++ii)
                #pragma unroll
                for (int jj = 0; jj < 8; ++jj) acc[ii][jj] = fmaf(xa[ii], cv[jj], acc[ii][jj]);
        }
        #pragma unroll
        for (int jj = 0; jj < 8; ++jj) {
            const int kl = (jj < 4) ? (ty * 4 + jj) : (64 + ty * 4 + (jj - 4));
            const float c2v = c2part[2 * kl] + c2part[2 * kl + 1];
            const int kglob = kc + kl;
            #pragma unroll
            for (int ii = 0; ii < 8; ++ii) {
                const float score = fmaf(-2.f, acc[ii][jj], c2v);
                if (score < vmin[ii]) { vmin[ii] = score; vidx[ii] = kglob; }
            }
        }
    }
    __syncthreads();
    float* redv = XT_s;
    int* redi = (int*)(XT_s + TN * 16);
    int* idxs = (int*)(XT_s + TN * 32);
    #pragma unroll
    for (int ii = 0; ii < 8; ++ii) {
        const int t = (ii < 4) ? (tx * 4 + ii) : (64 + tx * 4 + (ii - 4));
        redv[t * 16 + ty] = vmin[ii];
        redi[t * 16 + ty] = vidx[ii];
    }
    __syncthreads();
    if (tid < TN) {
        float bv = redv[tid * 16]; int bi = redi[tid * 16];
        #pragma unroll
        for (int j = 1; j < 16; ++j) {
            const float v = redv[tid * 16 + j]; const int id = redi[tid * 16 + j];
            if (v < bv || (v == bv && id < bi)) { bv = v; bi = id; }
        }
        idxs[tid] = bi;
    }
    __syncthreads();
    {
        const int tloc = tid & 127, chalf = tid >> 7;
        if (t0 + tloc < TT) {
            const int idx = idxs[tloc];
            const float* crow = cb + ((size_t)(band * NCODE + idx)) * CH;
            float* ob = out + ((size_t)(batch * NBAND + band) * CH) * TT + t0 + tloc;
            #pragma unroll
            for (int i = 0; i < 32; ++i) {
                const int c = chalf * 32 + i;
                ob[(size_t)c * TT] = crow[c];
            }
        }
    }
}

extern "C" void kernel_launch(void* const* d_in, const int* in_sizes, int n_in,
                              void* d_out, int out_size, void* d_ws, size_t ws_size,
                              hipStream_t stream) {
    const float* x  = (const float*)d_in[0];
    const float* cb = (const float*)d_in[1];
    float* out = (float*)d_out;
    dim3 grid((TT + MT - 1) / MT, NBAND, 2);
    if (ws_size >= WS_NEEDED) {
        unsigned short* CBF = (unsigned short*)d_ws;
        float* C2 = (float*)((char*)d_ws + CBF_BYTES);
        vq_prep<<<dim3(8, NBAND), dim3(256), 0, stream>>>(cb, CBF, C2);
        vq_main<<<grid, dim3(256), 0, stream>>>(x, cb, CBF, C2, out);
    } else {
        vq_fp32_kernel<<<grid, dim3(256), 0, stream>>>(x, cb, out);
    }
}